// Round 2
// baseline (447.740 us; speedup 1.0000x reference)
//
#include <hip/hip_runtime.h>
#include <stdint.h>

// Problem constants (n=6, d=1024, T=4096)
#define T_STEPS 4096
#define DDIM    1024
#define CHUNKS  128
#define CLEN    32   // T_STEPS / CHUNKS
#define MEAN_ELEMS ((size_t)T_STEPS * 6 * DDIM)   // 25,165,824

__device__ __forceinline__ float bf2f(uint16_t h){
    return __uint_as_float(((uint32_t)h) << 16);
}
__device__ __forceinline__ uint16_t f2bf(float f){   // round-to-nearest-even
    uint32_t u = __float_as_uint(f);
    uint32_t r = 0x7FFFu + ((u >> 16) & 1u);
    return (uint16_t)((u + r) >> 16);
}
// dtype-flag-aware scalar load (flag: 1 = inputs are float32, 0 = bf16)
__device__ __forceinline__ float ld(const void* p, size_t idx, bool f32){
    return f32 ? ((const float*)p)[idx] : bf2f(((const uint16_t*)p)[idx]);
}

// ---------------------------------------------------------------------------
// K0: input dtype detection. Looks at low 16 bits of first 3072 32-bit words
// of init_mean as bf16: true-bf16 input -> ~all sane N(0,1) magnitudes;
// f32 input -> low halves are mantissa garbage, ~13% sane. Writes flag.
// ---------------------------------------------------------------------------
__global__ void k0_detect(const void* __restrict__ imean, uint32_t* __restrict__ flag){
    const uint32_t* w = (const uint32_t*)imean;
    int good = 0;
    for (int i = threadIdx.x; i < 3072; i += 64){
        float v = bf2f((uint16_t)(w[i] & 0xFFFFu));
        float a = fabsf(v);
        if (a > 1e-6f && a < 1e4f) good++;
    }
    #pragma unroll
    for (int ofs = 32; ofs >= 1; ofs >>= 1) good += __shfl_xor(good, ofs, 64);
    if (threadIdx.x == 0) flag[0] = (good < 2000) ? 1u : 0u;
}

// ---------------------------------------------------------------------------
// K1: per-chunk composition of the covariance Gram recursion M' = A M A^T + N.
// Produces P_c (product of A's), Q_c (accumulated noise) in f64, plus f32
// copies of A (for the mean kernels) and P (for the mean boundary scan).
// ---------------------------------------------------------------------------
__global__ void k1_chunk_compose(const void* __restrict__ trans,
                                 const void* __restrict__ ncov,
                                 double* __restrict__ Pd, double* __restrict__ Qd,
                                 float* __restrict__ Af, float* __restrict__ Pf,
                                 const uint32_t* __restrict__ flag){
    __shared__ double A_ds[36], n_ds[36], P_ds[36], Q_ds[36], T_ds[36];
    const bool f32 = flag[0] != 0;
    const int c = blockIdx.x;
    const int e = threadIdx.x;
    const int i = e / 6, j = e % 6;
    if (e < 36){ P_ds[e] = (i == j) ? 1.0 : 0.0; Q_ds[e] = 0.0; }
    __syncthreads();
    for (int s = 0; s < CLEN; ++s){
        const int k = c * CLEN + s;
        if (e < 36){
            float a = ld(trans, (size_t)k*36 + e, f32);
            Af[k*36 + e] = a;
            A_ds[e] = (double)a;
            n_ds[e] = (double)ld(ncov, (size_t)k*36 + e, f32);
        }
        __syncthreads();
        double newP = 0.0, Tij = 0.0;
        if (e < 36){
            #pragma unroll
            for (int m = 0; m < 6; ++m){
                newP += A_ds[i*6+m] * P_ds[m*6+j];
                Tij  += A_ds[i*6+m] * Q_ds[m*6+j];
            }
        }
        __syncthreads();
        if (e < 36){ P_ds[e] = newP; T_ds[e] = Tij; }
        __syncthreads();
        double qn = 0.0;
        if (e < 36){
            #pragma unroll
            for (int m = 0; m < 6; ++m){
                qn += T_ds[i*6+m] * A_ds[j*6+m];   // (A Q) A^T
                qn += n_ds[i*6+m] * n_ds[j*6+m];   // + n n^T
            }
        }
        __syncthreads();
        if (e < 36) Q_ds[e] = qn;
        __syncthreads();
    }
    if (e < 36){
        Pd[c*36+e] = P_ds[e];
        Qd[c*36+e] = Q_ds[e];
        Pf[c*36+e] = (float)P_ds[e];
    }
}

// ---------------------------------------------------------------------------
// K2: sequential scan over chunk compositions -> M at each chunk start.
// ---------------------------------------------------------------------------
__global__ void k2_boundary_scan(const void* __restrict__ icov,
                                 const double* __restrict__ Pd,
                                 const double* __restrict__ Qd,
                                 double* __restrict__ Mb,
                                 const uint32_t* __restrict__ flag){
    __shared__ double M_ds[36], P_ds[36], T_ds[36], l_ds[36];
    const bool f32 = flag[0] != 0;
    const int e = threadIdx.x;
    const int i = e / 6, j = e % 6;
    if (e < 36) l_ds[e] = (double)ld(icov, e, f32);
    __syncthreads();
    if (e < 36){
        double m = 0.0;
        #pragma unroll
        for (int mm = 0; mm < 6; ++mm) m += l_ds[i*6+mm] * l_ds[j*6+mm];
        M_ds[e] = m; Mb[e] = m;
    }
    __syncthreads();
    for (int c = 0; c < CHUNKS - 1; ++c){
        double q = 0.0;
        if (e < 36){ P_ds[e] = Pd[c*36+e]; q = Qd[c*36+e]; }
        __syncthreads();
        double t = 0.0;
        if (e < 36){
            #pragma unroll
            for (int m = 0; m < 6; ++m) t += P_ds[i*6+m] * M_ds[m*6+j];
        }
        __syncthreads();
        if (e < 36) T_ds[e] = t;
        __syncthreads();
        double mn = 0.0;
        if (e < 36){
            #pragma unroll
            for (int m = 0; m < 6; ++m) mn += T_ds[i*6+m] * P_ds[j*6+m];
            mn += q;
        }
        __syncthreads();
        if (e < 36){ M_ds[e] = mn; Mb[(c+1)*36 + e] = mn; }
        __syncthreads();
    }
}

// ---------------------------------------------------------------------------
// K3: expand M to every step: Mall[k] = Gram entering step k. One wave/chunk.
// ---------------------------------------------------------------------------
__global__ void k3_expand_M(const void* __restrict__ trans,
                            const void* __restrict__ ncov,
                            const double* __restrict__ Mb,
                            double* __restrict__ Mall,
                            const uint32_t* __restrict__ flag){
    __shared__ double A_ds[36], n_ds[36], M_ds[36], T_ds[36];
    const bool f32 = flag[0] != 0;
    const int c = blockIdx.x;
    const int e = threadIdx.x;
    const int i = e / 6, j = e % 6;
    if (e < 36) M_ds[e] = Mb[c*36 + e];
    __syncthreads();
    for (int s = 0; s < CLEN; ++s){
        const int k = c * CLEN + s;
        if (e < 36) Mall[(size_t)k*36 + e] = M_ds[e];
        if (s == CLEN - 1) break;            // uniform branch
        if (e < 36){
            A_ds[e] = (double)ld(trans, (size_t)k*36 + e, f32);
            n_ds[e] = (double)ld(ncov,  (size_t)k*36 + e, f32);
        }
        __syncthreads();
        double t = 0.0;
        if (e < 36){
            #pragma unroll
            for (int m = 0; m < 6; ++m) t += A_ds[i*6+m] * M_ds[m*6+j];
        }
        __syncthreads();
        if (e < 36) T_ds[e] = t;
        __syncthreads();
        double mn = 0.0;
        if (e < 36){
            #pragma unroll
            for (int m = 0; m < 6; ++m){
                mn += T_ds[i*6+m] * A_ds[j*6+m];
                mn += n_ds[i*6+m] * n_ds[j*6+m];
            }
        }
        __syncthreads();
        if (e < 36) M_ds[e] = mn;
        __syncthreads();
    }
}

// ---------------------------------------------------------------------------
// K4: 4096 independent 12x6 Householder QRs (LAPACK dlarfg sign convention).
// k==0 uses the raw init_cov factor; k>=1 uses chol(Mall[k]). Emits unsigned
// l = R^T and the per-step diag-sign mask; signs fixed by K5/K6.
// Sign algebra: qr(diag(sigma,I)X).R == sigma * qr(X).R bitwise (Householder
// conjugation), so sigma_k = mask_k XOR sigma_{k-1}; seed = exact k=0 QR.
// ---------------------------------------------------------------------------
__global__ void __launch_bounds__(256)
k4_qr(const void* __restrict__ trans,
      const void* __restrict__ ncov,
      const void* __restrict__ icov,
      const double* __restrict__ Mall,
      void* __restrict__ d_out,
      uint32_t* __restrict__ masks,
      const uint32_t* __restrict__ flag){
    const int k = blockIdx.x * blockDim.x + threadIdx.x;
    if (k >= T_STEPS) return;
    const bool f32 = flag[0] != 0;
    double X[12][6];

    if (k == 0){
        double l0[6][6], A0[6][6];
        #pragma unroll
        for (int a = 0; a < 36; ++a){
            l0[a/6][a%6] = (double)ld(icov, a, f32);
            A0[a/6][a%6] = (double)ld(trans, a, f32);
        }
        #pragma unroll
        for (int i2 = 0; i2 < 6; ++i2)
            #pragma unroll
            for (int j2 = 0; j2 < 6; ++j2){
                double s = 0.0;
                #pragma unroll
                for (int m = 0; m < 6; ++m) s += A0[i2][m] * l0[m][j2];
                X[j2][i2] = s;               // top block = (A l)^T
            }
    } else {
        double M[6][6];
        #pragma unroll
        for (int a = 0; a < 36; ++a) M[a/6][a%6] = Mall[(size_t)k*36 + a];
        double C[6][6];
        #pragma unroll
        for (int j2 = 0; j2 < 6; ++j2){
            double d = M[j2][j2];
            #pragma unroll
            for (int m = 0; m < 6; ++m) if (m < j2) d -= C[j2][m]*C[j2][m];
            d = (d > 1e-300) ? d : 1e-300;
            double cjj = sqrt(d);
            C[j2][j2] = cjj;
            double inv = 1.0 / cjj;
            #pragma unroll
            for (int i2 = 0; i2 < 6; ++i2){
                if (i2 > j2){
                    double s = M[i2][j2];
                    #pragma unroll
                    for (int m = 0; m < 6; ++m) if (m < j2) s -= C[i2][m]*C[j2][m];
                    C[i2][j2] = s * inv;
                } else if (i2 < j2) C[i2][j2] = 0.0;
            }
        }
        #pragma unroll
        for (int i2 = 0; i2 < 6; ++i2){
            double Arow[6];
            #pragma unroll
            for (int m = 0; m < 6; ++m) Arow[m] = (double)ld(trans, (size_t)k*36 + i2*6 + m, f32);
            #pragma unroll
            for (int j2 = 0; j2 < 6; ++j2){
                double s = 0.0;
                #pragma unroll
                for (int m = 0; m < 6; ++m) s += Arow[m] * C[m][j2];
                X[j2][i2] = s;               // top block = (A C)^T
            }
        }
    }
    // bottom block = n^T
    #pragma unroll
    for (int r = 0; r < 6; ++r)
        #pragma unroll
        for (int c2 = 0; c2 < 6; ++c2)
            X[6+r][c2] = (double)ld(ncov, (size_t)k*36 + c2*6 + r, f32);

    // Householder QR with LAPACK sign convention: beta = -sign(alpha)*norm
    #pragma unroll
    for (int kk = 0; kk < 6; ++kk){
        double alpha = X[kk][kk];
        double xn2 = 0.0;
        #pragma unroll
        for (int i2 = 0; i2 < 12; ++i2) if (i2 > kk) xn2 += X[i2][kk]*X[i2][kk];
        if (xn2 != 0.0){
            double nrm  = sqrt(alpha*alpha + xn2);
            double beta = (alpha >= 0.0) ? -nrm : nrm;
            double tau  = (beta - alpha) / beta;
            double sc   = 1.0 / (alpha - beta);
            double v[12];
            #pragma unroll
            for (int i2 = 0; i2 < 12; ++i2) v[i2] = (i2 > kk) ? X[i2][kk]*sc : 0.0;
            X[kk][kk] = beta;
            #pragma unroll
            for (int j2 = 0; j2 < 6; ++j2){
                if (j2 > kk){
                    double w = X[kk][j2];
                    #pragma unroll
                    for (int i2 = 0; i2 < 12; ++i2) if (i2 > kk) w += v[i2]*X[i2][j2];
                    double wt = tau * w;
                    X[kk][j2] -= wt;
                    #pragma unroll
                    for (int i2 = 0; i2 < 12; ++i2) if (i2 > kk) X[i2][j2] -= v[i2]*wt;
                }
            }
        } // xn2==0: H=I, R[kk][kk]=alpha (LAPACK), nothing to do
    }

    uint32_t mask = 0;
    #pragma unroll
    for (int j2 = 0; j2 < 6; ++j2) if (X[j2][j2] < 0.0) mask |= (1u << j2);
    masks[k] = mask;

    if (f32){
        float* o = (float*)d_out + MEAN_ELEMS + (size_t)k*36;
        #pragma unroll
        for (int i2 = 0; i2 < 6; ++i2)
            #pragma unroll
            for (int j2 = 0; j2 < 6; ++j2)
                o[i2*6 + j2] = (j2 <= i2) ? (float)X[j2][i2] : 0.0f;
    } else {
        uint16_t* o = (uint16_t*)d_out + MEAN_ELEMS + (size_t)k*36;
        #pragma unroll
        for (int i2 = 0; i2 < 6; ++i2)
            #pragma unroll
            for (int j2 = 0; j2 < 6; ++j2)
                o[i2*6 + j2] = f2bf((j2 <= i2) ? (float)X[j2][i2] : 0.0f);
    }
}

// K5: XOR prefix-scan of sign masks. amask[k] = masks[0]^...^masks[k-1].
__global__ void k5_scan(const uint32_t* __restrict__ masks, uint32_t* __restrict__ amask){
    const int lane = threadIdx.x;
    const int base = lane * 64;
    uint32_t tot = 0;
    for (int i2 = 0; i2 < 64; ++i2) tot ^= masks[base + i2];
    uint32_t incl = tot;
    #pragma unroll
    for (int ofs = 1; ofs < 64; ofs <<= 1){
        uint32_t up = (uint32_t)__shfl_up((int)incl, ofs, 64);
        if (lane >= ofs) incl ^= up;
    }
    uint32_t run = incl ^ tot;               // exclusive prefix of lane segment
    for (int i2 = 0; i2 < 64; ++i2){
        amask[base + i2] = run;
        run ^= masks[base + i2];
    }
}

// K6: apply column sign flips to covs[k], k>=1 (sign-bit XOR, dtype-aware).
__global__ void k6_apply(void* __restrict__ d_out, const uint32_t* __restrict__ amask,
                         const uint32_t* __restrict__ flag){
    const int k = blockIdx.x;
    const int e = threadIdx.x;
    if (k == 0 || e >= 36) return;
    const uint32_t m = amask[k];
    if (!((m >> (e % 6)) & 1u)) return;
    if (flag[0]) ((uint32_t*)d_out)[MEAN_ELEMS + (size_t)k*36 + e] ^= 0x80000000u;
    else         ((uint16_t*)d_out)[MEAN_ELEMS + (size_t)k*36 + e] ^= 0x8000u;
}

// ---------------------------------------------------------------------------
// Means pipeline: m_t = A_t m_{t-1} + b_t, columns independent. 3-phase scan.
// ---------------------------------------------------------------------------
template<bool F32>
__device__ __forceinline__ void km1_body(const void* nmean, const float* Af,
                                         float* r_ws, int c, int col){
    float r0[6], r1[6];
    #pragma unroll
    for (int i = 0; i < 6; ++i){ r0[i] = 0.f; r1[i] = 0.f; }
    for (int s = 0; s < CLEN; ++s){
        const int k = c*CLEN + s;
        const float* A = Af + (size_t)k*36;   // uniform address -> scalar loads
        float a[36];
        #pragma unroll
        for (int t = 0; t < 36; ++t) a[t] = A[t];
        float n0[6], n1[6];
        #pragma unroll
        for (int i = 0; i < 6; ++i){
            float s0, s1;
            if (F32){
                float2 u = *(const float2*)((const float*)nmean + (size_t)k*6144 + i*DDIM + col);
                s0 = u.x; s1 = u.y;
            } else {
                uint32_t u = *(const uint32_t*)((const uint16_t*)nmean + (size_t)k*6144 + i*DDIM + col);
                s0 = __uint_as_float(u << 16);
                s1 = __uint_as_float(u & 0xFFFF0000u);
            }
            #pragma unroll
            for (int m = 0; m < 6; ++m){ s0 += a[i*6+m]*r0[m]; s1 += a[i*6+m]*r1[m]; }
            n0[i] = s0; n1[i] = s1;
        }
        #pragma unroll
        for (int i = 0; i < 6; ++i){ r0[i] = n0[i]; r1[i] = n1[i]; }
    }
    float* out = r_ws + (size_t)c*6144;
    #pragma unroll
    for (int i = 0; i < 6; ++i){ out[i*DDIM + col] = r0[i]; out[i*DDIM + col + 1] = r1[i]; }
}

__global__ void __launch_bounds__(256)
km1_chunk_r(const void* __restrict__ nmean, const float* __restrict__ Af,
            float* __restrict__ r_ws, const uint32_t* __restrict__ flag){
    const int c    = blockIdx.x >> 1;
    const int half = blockIdx.x & 1;
    const int col  = half*512 + threadIdx.x*2;
    if (flag[0]) km1_body<true>(nmean, Af, r_ws, c, col);
    else         km1_body<false>(nmean, Af, r_ws, c, col);
}

// KM2: sequential chunk-boundary scan of means.
__global__ void km2_scan(const void* __restrict__ imean,
                         const float* __restrict__ Pf,
                         const float* __restrict__ r_ws,
                         float* __restrict__ mb_ws,
                         const uint32_t* __restrict__ flag){
    const bool f32 = flag[0] != 0;
    const int col = blockIdx.x*512 + threadIdx.x*2;
    float m0[6], m1[6];
    #pragma unroll
    for (int i = 0; i < 6; ++i){
        if (f32){
            float2 u = *(const float2*)((const float*)imean + i*DDIM + col);
            m0[i] = u.x; m1[i] = u.y;
        } else {
            uint32_t u = *(const uint32_t*)((const uint16_t*)imean + i*DDIM + col);
            m0[i] = __uint_as_float(u << 16);
            m1[i] = __uint_as_float(u & 0xFFFF0000u);
        }
    }
    for (int c = 0; c < CHUNKS; ++c){
        float* mb = mb_ws + (size_t)c*6144;
        #pragma unroll
        for (int i = 0; i < 6; ++i){ mb[i*DDIM + col] = m0[i]; mb[i*DDIM + col + 1] = m1[i]; }
        const float* P = Pf + (size_t)c*36;
        float p[36];
        #pragma unroll
        for (int t = 0; t < 36; ++t) p[t] = P[t];
        const float* r = r_ws + (size_t)c*6144;
        float n0[6], n1[6];
        #pragma unroll
        for (int i = 0; i < 6; ++i){
            float s0 = r[i*DDIM + col], s1 = r[i*DDIM + col + 1];
            #pragma unroll
            for (int m = 0; m < 6; ++m){ s0 += p[i*6+m]*m0[m]; s1 += p[i*6+m]*m1[m]; }
            n0[i] = s0; n1[i] = s1;
        }
        #pragma unroll
        for (int i = 0; i < 6; ++i){ m0[i] = n0[i]; m1[i] = n1[i]; }
    }
}

// KM3: replay within chunk from exact boundary, write means (dtype-aware).
template<bool F32>
__device__ __forceinline__ void km3_body(const void* nmean, const float* Af,
                                         const float* mb_ws, void* means_out,
                                         int c, int col){
    float m0[6], m1[6];
    const float* mb = mb_ws + (size_t)c*6144;
    #pragma unroll
    for (int i = 0; i < 6; ++i){ m0[i] = mb[i*DDIM + col]; m1[i] = mb[i*DDIM + col + 1]; }
    for (int s = 0; s < CLEN; ++s){
        const int k = c*CLEN + s;
        const float* A = Af + (size_t)k*36;
        float a[36];
        #pragma unroll
        for (int t = 0; t < 36; ++t) a[t] = A[t];
        float n0[6], n1[6];
        #pragma unroll
        for (int i = 0; i < 6; ++i){
            float s0, s1;
            if (F32){
                float2 u = *(const float2*)((const float*)nmean + (size_t)k*6144 + i*DDIM + col);
                s0 = u.x; s1 = u.y;
            } else {
                uint32_t u = *(const uint32_t*)((const uint16_t*)nmean + (size_t)k*6144 + i*DDIM + col);
                s0 = __uint_as_float(u << 16);
                s1 = __uint_as_float(u & 0xFFFF0000u);
            }
            #pragma unroll
            for (int m = 0; m < 6; ++m){ s0 += a[i*6+m]*m0[m]; s1 += a[i*6+m]*m1[m]; }
            n0[i] = s0; n1[i] = s1;
        }
        #pragma unroll
        for (int i = 0; i < 6; ++i){
            m0[i] = n0[i]; m1[i] = n1[i];
            if (F32){
                *(float2*)((float*)means_out + (size_t)k*6144 + i*DDIM + col) = make_float2(m0[i], m1[i]);
            } else {
                uint32_t packed = (uint32_t)f2bf(m0[i]) | ((uint32_t)f2bf(m1[i]) << 16);
                *(uint32_t*)((uint16_t*)means_out + (size_t)k*6144 + i*DDIM + col) = packed;
            }
        }
    }
}

__global__ void __launch_bounds__(256)
km3_final(const void* __restrict__ nmean, const float* __restrict__ Af,
          const float* __restrict__ mb_ws, void* __restrict__ means_out,
          const uint32_t* __restrict__ flag){
    const int c    = blockIdx.x >> 1;
    const int half = blockIdx.x & 1;
    const int col  = half*512 + threadIdx.x*2;
    if (flag[0]) km3_body<true>(nmean, Af, mb_ws, means_out, c, col);
    else         km3_body<false>(nmean, Af, mb_ws, means_out, c, col);
}

// ---------------------------------------------------------------------------
extern "C" void kernel_launch(void* const* d_in, const int* in_sizes, int n_in,
                              void* d_out, int out_size, void* d_ws, size_t ws_size,
                              hipStream_t stream){
    (void)in_sizes; (void)n_in; (void)out_size; (void)ws_size;
    const void* imean = d_in[0];  // [6,1024]
    const void* icov  = d_in[1];  // [6,6]
    const void* trans = d_in[2];  // [T,6,6]
    const void* nmean = d_in[3];  // [T,6,1024]
    const void* ncov  = d_in[4];  // [T,6,6]

    // workspace layout (8-byte types first; ~8.3 MB total)
    char* w = (char*)d_ws;
    double* Pd   = (double*)w; w += (size_t)CHUNKS*36*8;
    double* Qd   = (double*)w; w += (size_t)CHUNKS*36*8;
    double* Mb   = (double*)w; w += (size_t)CHUNKS*36*8;
    double* Mall = (double*)w; w += (size_t)T_STEPS*36*8;
    float*  Af   = (float*)w;  w += (size_t)T_STEPS*36*4;
    float*  Pf   = (float*)w;  w += (size_t)CHUNKS*36*4;
    uint32_t* masks = (uint32_t*)w; w += (size_t)T_STEPS*4;
    uint32_t* amask = (uint32_t*)w; w += (size_t)T_STEPS*4;
    uint32_t* flag  = (uint32_t*)w; w += 8;
    float* r_ws  = (float*)w;  w += (size_t)CHUNKS*6*DDIM*4;
    float* mb_ws = (float*)w;  w += (size_t)CHUNKS*6*DDIM*4;

    k0_detect<<<1, 64, 0, stream>>>(imean, flag);
    k1_chunk_compose<<<CHUNKS, 64, 0, stream>>>(trans, ncov, Pd, Qd, Af, Pf, flag);
    km1_chunk_r<<<2*CHUNKS, 256, 0, stream>>>(nmean, Af, r_ws, flag);
    km2_scan<<<2, 256, 0, stream>>>(imean, Pf, r_ws, mb_ws, flag);
    km3_final<<<2*CHUNKS, 256, 0, stream>>>(nmean, Af, mb_ws, d_out, flag);
    k2_boundary_scan<<<1, 64, 0, stream>>>(icov, Pd, Qd, Mb, flag);
    k3_expand_M<<<CHUNKS, 64, 0, stream>>>(trans, ncov, Mb, Mall, flag);
    k4_qr<<<T_STEPS/256, 256, 0, stream>>>(trans, ncov, icov, Mall, d_out, masks, flag);
    k5_scan<<<1, 64, 0, stream>>>(masks, amask);
    k6_apply<<<T_STEPS, 64, 0, stream>>>(d_out, amask, flag);
}

// Round 3
// 396.972 us; speedup vs baseline: 1.1279x; 1.1279x over previous
//
#include <hip/hip_runtime.h>
#include <stdint.h>

// Problem constants (n=6, d=1024, T=4096)
#define T_STEPS 4096
#define DDIM    1024
#define CH      64    // chunks (both pipelines)
#define CL      64    // steps per chunk
#define MEAN_ELEMS ((size_t)T_STEPS * 6 * DDIM)   // 25,165,824

__device__ __forceinline__ float bf2f(uint16_t h){
    return __uint_as_float(((uint32_t)h) << 16);
}
__device__ __forceinline__ uint16_t f2bf(float f){   // round-to-nearest-even
    uint32_t u = __float_as_uint(f);
    uint32_t r = 0x7FFFu + ((u >> 16) & 1u);
    return (uint16_t)((u + r) >> 16);
}
// dtype-flag-aware scalar load (flag: 1 = inputs are float32, 0 = bf16)
__device__ __forceinline__ float ld(const void* p, size_t idx, bool f32){
    return f32 ? ((const float*)p)[idx] : bf2f(((const uint16_t*)p)[idx]);
}

// ---------------------------------------------------------------------------
// K0: input dtype detection (low 16 bits of f32 words are mantissa garbage).
// ---------------------------------------------------------------------------
__global__ void k0_detect(const void* __restrict__ imean, uint32_t* __restrict__ flag){
    const uint32_t* w = (const uint32_t*)imean;
    int good = 0;
    for (int i = threadIdx.x; i < 3072; i += 64){
        float v = bf2f((uint16_t)(w[i] & 0xFFFFu));
        float a = fabsf(v);
        if (a > 1e-6f && a < 1e4f) good++;
    }
    #pragma unroll
    for (int ofs = 32; ofs >= 1; ofs >>= 1) good += __shfl_xor(good, ofs, 64);
    if (threadIdx.x == 0) flag[0] = (good < 2000) ? 1u : 0u;
}

// ---------------------------------------------------------------------------
// K1: per-chunk composition M' = A M A^T + N (Gram recursion), 64-step chunks.
// Register-prefetches next step's A/n during the current matmul phases.
// Outputs: Pd,Qd (f64), Pf (f32, for mean boundary scan), Af (f32 trans copy).
// ---------------------------------------------------------------------------
__global__ void k1_chunk_compose(const void* __restrict__ trans,
                                 const void* __restrict__ ncov,
                                 double* __restrict__ Pd, double* __restrict__ Qd,
                                 float* __restrict__ Af, float* __restrict__ Pf,
                                 const uint32_t* __restrict__ flag){
    __shared__ double A_ds[36], n_ds[36], P_ds[36], Q_ds[36], T_ds[36];
    const bool f32 = flag[0] != 0;
    const int c = blockIdx.x;
    const int e = threadIdx.x;
    const int i = e / 6, j = e % 6;
    float aCur = 0.f, nCur = 0.f;
    if (e < 36){
        P_ds[e] = (i == j) ? 1.0 : 0.0; Q_ds[e] = 0.0;
        aCur = ld(trans, (size_t)c*CL*36 + e, f32);
        nCur = ld(ncov,  (size_t)c*CL*36 + e, f32);
    }
    __syncthreads();
    for (int s = 0; s < CL; ++s){
        const int k = c * CL + s;
        if (e < 36){
            Af[k*36 + e] = aCur;
            A_ds[e] = (double)aCur;
            n_ds[e] = (double)nCur;
        }
        __syncthreads();
        // issue next step's independent loads now (hidden behind matmuls)
        if (e < 36 && s + 1 < CL){
            aCur = ld(trans, (size_t)(k+1)*36 + e, f32);
            nCur = ld(ncov,  (size_t)(k+1)*36 + e, f32);
        }
        double newP = 0.0, Tij = 0.0;
        if (e < 36){
            #pragma unroll
            for (int m = 0; m < 6; ++m){
                newP += A_ds[i*6+m] * P_ds[m*6+j];
                Tij  += A_ds[i*6+m] * Q_ds[m*6+j];
            }
        }
        __syncthreads();
        if (e < 36){ P_ds[e] = newP; T_ds[e] = Tij; }
        __syncthreads();
        double qn = 0.0;
        if (e < 36){
            #pragma unroll
            for (int m = 0; m < 6; ++m){
                qn += T_ds[i*6+m] * A_ds[j*6+m];   // (A Q) A^T
                qn += n_ds[i*6+m] * n_ds[j*6+m];   // + n n^T
            }
        }
        __syncthreads();
        if (e < 36) Q_ds[e] = qn;
        __syncthreads();
    }
    if (e < 36){
        Pd[c*36+e] = P_ds[e];
        Qd[c*36+e] = Q_ds[e];
        Pf[c*36+e] = (float)P_ds[e];
    }
}

// ---------------------------------------------------------------------------
// K2: boundary scan, ALL (P,Q) preloaded to LDS (64*72*8 = 36.9 KB).
// Single wave; serial loop runs entirely from LDS.
// ---------------------------------------------------------------------------
__global__ void k2_boundary_scan(const void* __restrict__ icov,
                                 const double* __restrict__ Pd,
                                 const double* __restrict__ Qd,
                                 double* __restrict__ Mb,
                                 const uint32_t* __restrict__ flag){
    __shared__ double Ps[CH][36], Qs[CH][36];
    __shared__ double M_ds[36], T_ds[36], l_ds[36];
    const bool f32 = flag[0] != 0;
    const int e = threadIdx.x;
    const int i = e / 6, j = e % 6;
    for (int idx = e; idx < CH*36; idx += 64){
        Ps[idx/36][idx%36] = Pd[idx];
        Qs[idx/36][idx%36] = Qd[idx];
    }
    if (e < 36) l_ds[e] = (double)ld(icov, e, f32);
    __syncthreads();
    if (e < 36){
        double m = 0.0;
        #pragma unroll
        for (int mm = 0; mm < 6; ++mm) m += l_ds[i*6+mm] * l_ds[j*6+mm];
        M_ds[e] = m; Mb[e] = m;
    }
    __syncthreads();
    for (int c = 0; c < CH - 1; ++c){
        double t = 0.0;
        if (e < 36){
            #pragma unroll
            for (int m = 0; m < 6; ++m) t += Ps[c][i*6+m] * M_ds[m*6+j];
        }
        __syncthreads();
        if (e < 36) T_ds[e] = t;
        __syncthreads();
        double mn = 0.0;
        if (e < 36){
            #pragma unroll
            for (int m = 0; m < 6; ++m) mn += T_ds[i*6+m] * Ps[c][j*6+m];
            mn += Qs[c][e];
        }
        __syncthreads();
        if (e < 36){ M_ds[e] = mn; Mb[(c+1)*36 + e] = mn; }
        __syncthreads();
    }
}

// ---------------------------------------------------------------------------
// K3: expand M to every step (Gram entering step k), with A/n prefetch.
// ---------------------------------------------------------------------------
__global__ void k3_expand_M(const void* __restrict__ trans,
                            const void* __restrict__ ncov,
                            const double* __restrict__ Mb,
                            double* __restrict__ Mall,
                            const uint32_t* __restrict__ flag){
    __shared__ double A_ds[36], n_ds[36], M_ds[36], T_ds[36];
    const bool f32 = flag[0] != 0;
    const int c = blockIdx.x;
    const int e = threadIdx.x;
    const int i = e / 6, j = e % 6;
    float aCur = 0.f, nCur = 0.f;
    if (e < 36){
        M_ds[e] = Mb[c*36 + e];
        aCur = ld(trans, (size_t)c*CL*36 + e, f32);
        nCur = ld(ncov,  (size_t)c*CL*36 + e, f32);
    }
    __syncthreads();
    for (int s = 0; s < CL; ++s){
        const int k = c * CL + s;
        if (e < 36) Mall[(size_t)k*36 + e] = M_ds[e];
        if (s == CL - 1) break;              // uniform branch
        if (e < 36){
            A_ds[e] = (double)aCur;
            n_ds[e] = (double)nCur;
        }
        __syncthreads();
        if (e < 36 && s + 2 < CL){
            aCur = ld(trans, (size_t)(k+2)*36 + e - 36 + 36, f32); // (k+1)*36+e
            aCur = ld(trans, (size_t)(k+1)*36 + e, f32);
            nCur = ld(ncov,  (size_t)(k+1)*36 + e, f32);
        } else if (e < 36 && s + 1 < CL - 1){
            aCur = ld(trans, (size_t)(k+1)*36 + e, f32);
            nCur = ld(ncov,  (size_t)(k+1)*36 + e, f32);
        }
        double t = 0.0;
        if (e < 36){
            #pragma unroll
            for (int m = 0; m < 6; ++m) t += A_ds[i*6+m] * M_ds[m*6+j];
        }
        __syncthreads();
        if (e < 36) T_ds[e] = t;
        __syncthreads();
        double mn = 0.0;
        if (e < 36){
            #pragma unroll
            for (int m = 0; m < 6; ++m){
                mn += T_ds[i*6+m] * A_ds[j*6+m];
                mn += n_ds[i*6+m] * n_ds[j*6+m];
            }
        }
        __syncthreads();
        if (e < 36) M_ds[e] = mn;
        __syncthreads();
    }
}

// ---------------------------------------------------------------------------
// K4: 4096 independent 12x6 Householder QRs, f64, in-place (Cholesky over M,
// Householder v stored in X) to keep VGPRs ~230 (no spill). LAPACK dlarfg
// sign convention. Sign algebra: qr(diag(sigma,I)X).R == sigma*qr(X).R
// bitwise, so sigma_k = mask_k XOR sigma_{k-1}; seed = exact k=0 QR.
// ---------------------------------------------------------------------------
__global__ void __launch_bounds__(64)
k4_qr(const void* __restrict__ trans,
      const void* __restrict__ ncov,
      const void* __restrict__ icov,
      const double* __restrict__ Mall,
      void* __restrict__ d_out,
      uint32_t* __restrict__ masks,
      const uint32_t* __restrict__ flag){
    const int k = blockIdx.x * blockDim.x + threadIdx.x;
    if (k >= T_STEPS) return;
    const bool f32 = flag[0] != 0;
    double X[12][6];

    if (k == 0){
        double l0[6][6], A0[6][6];
        #pragma unroll
        for (int a = 0; a < 36; ++a){
            l0[a/6][a%6] = (double)ld(icov, a, f32);
            A0[a/6][a%6] = (double)ld(trans, a, f32);
        }
        #pragma unroll
        for (int i2 = 0; i2 < 6; ++i2)
            #pragma unroll
            for (int j2 = 0; j2 < 6; ++j2){
                double s = 0.0;
                #pragma unroll
                for (int m = 0; m < 6; ++m) s += A0[i2][m] * l0[m][j2];
                X[j2][i2] = s;               // top block = (A l)^T
            }
    } else {
        double M[6][6];
        #pragma unroll
        for (int a = 0; a < 36; ++a) M[a/6][a%6] = Mall[(size_t)k*36 + a];
        // Cholesky in place (lower triangle of M becomes C)
        #pragma unroll
        for (int j2 = 0; j2 < 6; ++j2){
            double d = M[j2][j2];
            #pragma unroll
            for (int m = 0; m < 6; ++m) if (m < j2) d -= M[j2][m]*M[j2][m];
            d = (d > 1e-300) ? d : 1e-300;
            double cjj = sqrt(d);
            M[j2][j2] = cjj;
            double inv = 1.0 / cjj;
            #pragma unroll
            for (int i2 = 0; i2 < 6; ++i2){
                if (i2 > j2){
                    double s = M[i2][j2];
                    #pragma unroll
                    for (int m = 0; m < 6; ++m) if (m < j2) s -= M[i2][m]*M[j2][m];
                    M[i2][j2] = s * inv;
                }
            }
        }
        #pragma unroll
        for (int i2 = 0; i2 < 6; ++i2){
            double Arow[6];
            #pragma unroll
            for (int m = 0; m < 6; ++m) Arow[m] = (double)ld(trans, (size_t)k*36 + i2*6 + m, f32);
            #pragma unroll
            for (int j2 = 0; j2 < 6; ++j2){
                double s = 0.0;
                #pragma unroll
                for (int m = 0; m < 6; ++m) if (m >= j2) s += Arow[m] * M[m][j2];
                X[j2][i2] = s;               // top block = (A C)^T
            }
        }
    }
    // bottom block = n^T
    #pragma unroll
    for (int r = 0; r < 6; ++r)
        #pragma unroll
        for (int c2 = 0; c2 < 6; ++c2)
            X[6+r][c2] = (double)ld(ncov, (size_t)k*36 + c2*6 + r, f32);

    // In-place Householder QR, LAPACK sign convention: beta = -sign(alpha)*norm
    #pragma unroll
    for (int kk = 0; kk < 6; ++kk){
        double alpha = X[kk][kk];
        double xn2 = 0.0;
        #pragma unroll
        for (int i2 = 0; i2 < 12; ++i2) if (i2 > kk) xn2 += X[i2][kk]*X[i2][kk];
        if (xn2 != 0.0){
            double nrm  = sqrt(alpha*alpha + xn2);
            double beta = (alpha >= 0.0) ? -nrm : nrm;
            double tau  = (beta - alpha) / beta;
            double sc   = 1.0 / (alpha - beta);
            #pragma unroll
            for (int i2 = 0; i2 < 12; ++i2) if (i2 > kk) X[i2][kk] *= sc;  // v in place
            X[kk][kk] = beta;
            #pragma unroll
            for (int j2 = 0; j2 < 6; ++j2){
                if (j2 > kk){
                    double w = X[kk][j2];
                    #pragma unroll
                    for (int i2 = 0; i2 < 12; ++i2) if (i2 > kk) w += X[i2][kk]*X[i2][j2];
                    double wt = tau * w;
                    X[kk][j2] -= wt;
                    #pragma unroll
                    for (int i2 = 0; i2 < 12; ++i2) if (i2 > kk) X[i2][j2] -= X[i2][kk]*wt;
                }
            }
        } // xn2==0: H=I, R[kk][kk]=alpha (LAPACK), nothing to do
    }

    uint32_t mask = 0;
    #pragma unroll
    for (int j2 = 0; j2 < 6; ++j2) if (X[j2][j2] < 0.0) mask |= (1u << j2);
    masks[k] = mask;

    if (f32){
        float* o = (float*)d_out + MEAN_ELEMS + (size_t)k*36;
        #pragma unroll
        for (int i2 = 0; i2 < 6; ++i2)
            #pragma unroll
            for (int j2 = 0; j2 < 6; ++j2)
                o[i2*6 + j2] = (j2 <= i2) ? (float)X[j2][i2] : 0.0f;
    } else {
        uint16_t* o = (uint16_t*)d_out + MEAN_ELEMS + (size_t)k*36;
        #pragma unroll
        for (int i2 = 0; i2 < 6; ++i2)
            #pragma unroll
            for (int j2 = 0; j2 < 6; ++j2)
                o[i2*6 + j2] = f2bf((j2 <= i2) ? (float)X[j2][i2] : 0.0f);
    }
}

// K5: XOR prefix-scan of sign masks. amask[k] = masks[0]^...^masks[k-1].
__global__ void k5_scan(const uint32_t* __restrict__ masks, uint32_t* __restrict__ amask){
    const int lane = threadIdx.x;
    const int base = lane * 64;
    uint32_t tot = 0;
    for (int i2 = 0; i2 < 64; ++i2) tot ^= masks[base + i2];
    uint32_t incl = tot;
    #pragma unroll
    for (int ofs = 1; ofs < 64; ofs <<= 1){
        uint32_t up = (uint32_t)__shfl_up((int)incl, ofs, 64);
        if (lane >= ofs) incl ^= up;
    }
    uint32_t run = incl ^ tot;               // exclusive prefix of lane segment
    for (int i2 = 0; i2 < 64; ++i2){
        amask[base + i2] = run;
        run ^= masks[base + i2];
    }
}

// K6: apply column sign flips to covs[k], k>=1 (sign-bit XOR, dtype-aware).
__global__ void k6_apply(void* __restrict__ d_out, const uint32_t* __restrict__ amask,
                         const uint32_t* __restrict__ flag){
    const int k = blockIdx.x;
    const int e = threadIdx.x;
    if (k == 0 || e >= 36) return;
    const uint32_t m = amask[k];
    if (!((m >> (e % 6)) & 1u)) return;
    if (flag[0]) ((uint32_t*)d_out)[MEAN_ELEMS + (size_t)k*36 + e] ^= 0x80000000u;
    else         ((uint16_t*)d_out)[MEAN_ELEMS + (size_t)k*36 + e] ^= 0x8000u;
}

// ---------------------------------------------------------------------------
// Means pipeline: m_t = A_t m_{t-1} + b_t, 3-phase chunked scan (64x64).
// ---------------------------------------------------------------------------
template<bool F32>
__device__ __forceinline__ void km1_body(const void* nmean, const float* Af,
                                         float* r_ws, int c, int col){
    float r0[6], r1[6];
    #pragma unroll
    for (int i = 0; i < 6; ++i){ r0[i] = 0.f; r1[i] = 0.f; }
    for (int s = 0; s < CL; ++s){
        const int k = c*CL + s;
        const float* A = Af + (size_t)k*36;
        float a[36];
        #pragma unroll
        for (int t = 0; t < 36; ++t) a[t] = A[t];
        float n0[6], n1[6];
        #pragma unroll
        for (int i = 0; i < 6; ++i){
            float s0, s1;
            if (F32){
                float2 u = *(const float2*)((const float*)nmean + (size_t)k*6144 + i*DDIM + col);
                s0 = u.x; s1 = u.y;
            } else {
                uint32_t u = *(const uint32_t*)((const uint16_t*)nmean + (size_t)k*6144 + i*DDIM + col);
                s0 = __uint_as_float(u << 16);
                s1 = __uint_as_float(u & 0xFFFF0000u);
            }
            #pragma unroll
            for (int m = 0; m < 6; ++m){ s0 += a[i*6+m]*r0[m]; s1 += a[i*6+m]*r1[m]; }
            n0[i] = s0; n1[i] = s1;
        }
        #pragma unroll
        for (int i = 0; i < 6; ++i){ r0[i] = n0[i]; r1[i] = n1[i]; }
    }
    float* out = r_ws + (size_t)c*6144;
    #pragma unroll
    for (int i = 0; i < 6; ++i){ out[i*DDIM + col] = r0[i]; out[i*DDIM + col + 1] = r1[i]; }
}

__global__ void __launch_bounds__(256)
km1_chunk_r(const void* __restrict__ nmean, const float* __restrict__ Af,
            float* __restrict__ r_ws, const uint32_t* __restrict__ flag){
    const int c    = blockIdx.x >> 1;
    const int half = blockIdx.x & 1;
    const int col  = half*512 + threadIdx.x*2;
    if (flag[0]) km1_body<true>(nmean, Af, r_ws, c, col);
    else         km1_body<false>(nmean, Af, r_ws, c, col);
}

// KM2: chunk-boundary scan with 1-chunk-ahead register prefetch of r and P.
__global__ void __launch_bounds__(256)
km2_scan(const void* __restrict__ imean,
         const float* __restrict__ Pf,
         const float* __restrict__ r_ws,
         float* __restrict__ mb_ws,
         const uint32_t* __restrict__ flag){
    const bool f32 = flag[0] != 0;
    const int col = blockIdx.x*256 + threadIdx.x;   // 4 blocks x 256 = 1024 cols
    float m[6];
    #pragma unroll
    for (int i = 0; i < 6; ++i) m[i] = ld(imean, (size_t)i*DDIM + col, f32);
    float rA[6], pA[36];
    #pragma unroll
    for (int i = 0; i < 6; ++i) rA[i] = r_ws[i*DDIM + col];
    #pragma unroll
    for (int t = 0; t < 36; ++t) pA[t] = Pf[t];
    for (int c = 0; c < CH; ++c){
        float rB[6], pB[36];
        if (c + 1 < CH){                     // independent loads: issue early
            const float* rn = r_ws + (size_t)(c+1)*6144;
            #pragma unroll
            for (int i = 0; i < 6; ++i) rB[i] = rn[i*DDIM + col];
            const float* pn = Pf + (size_t)(c+1)*36;
            #pragma unroll
            for (int t = 0; t < 36; ++t) pB[t] = pn[t];
        }
        float* mb = mb_ws + (size_t)c*6144;
        #pragma unroll
        for (int i = 0; i < 6; ++i) mb[i*DDIM + col] = m[i];
        float nm[6];
        #pragma unroll
        for (int i = 0; i < 6; ++i){
            float s0 = rA[i];
            #pragma unroll
            for (int mm = 0; mm < 6; ++mm) s0 += pA[i*6+mm]*m[mm];
            nm[i] = s0;
        }
        #pragma unroll
        for (int i = 0; i < 6; ++i) m[i] = nm[i];
        if (c + 1 < CH){
            #pragma unroll
            for (int i = 0; i < 6; ++i) rA[i] = rB[i];
            #pragma unroll
            for (int t = 0; t < 36; ++t) pA[t] = pB[t];
        }
    }
}

// KM3: replay within chunk from exact boundary, write means (dtype-aware).
template<bool F32>
__device__ __forceinline__ void km3_body(const void* nmean, const float* Af,
                                         const float* mb_ws, void* means_out,
                                         int c, int col){
    float m0[6], m1[6];
    const float* mb = mb_ws + (size_t)c*6144;
    #pragma unroll
    for (int i = 0; i < 6; ++i){ m0[i] = mb[i*DDIM + col]; m1[i] = mb[i*DDIM + col + 1]; }
    for (int s = 0; s < CL; ++s){
        const int k = c*CL + s;
        const float* A = Af + (size_t)k*36;
        float a[36];
        #pragma unroll
        for (int t = 0; t < 36; ++t) a[t] = A[t];
        float n0[6], n1[6];
        #pragma unroll
        for (int i = 0; i < 6; ++i){
            float s0, s1;
            if (F32){
                float2 u = *(const float2*)((const float*)nmean + (size_t)k*6144 + i*DDIM + col);
                s0 = u.x; s1 = u.y;
            } else {
                uint32_t u = *(const uint32_t*)((const uint16_t*)nmean + (size_t)k*6144 + i*DDIM + col);
                s0 = __uint_as_float(u << 16);
                s1 = __uint_as_float(u & 0xFFFF0000u);
            }
            #pragma unroll
            for (int m = 0; m < 6; ++m){ s0 += a[i*6+m]*m0[m]; s1 += a[i*6+m]*m1[m]; }
            n0[i] = s0; n1[i] = s1;
        }
        #pragma unroll
        for (int i = 0; i < 6; ++i){
            m0[i] = n0[i]; m1[i] = n1[i];
            if (F32){
                *(float2*)((float*)means_out + (size_t)k*6144 + i*DDIM + col) = make_float2(m0[i], m1[i]);
            } else {
                uint32_t packed = (uint32_t)f2bf(m0[i]) | ((uint32_t)f2bf(m1[i]) << 16);
                *(uint32_t*)((uint16_t*)means_out + (size_t)k*6144 + i*DDIM + col) = packed;
            }
        }
    }
}

__global__ void __launch_bounds__(256)
km3_final(const void* __restrict__ nmean, const float* __restrict__ Af,
          const float* __restrict__ mb_ws, void* __restrict__ means_out,
          const uint32_t* __restrict__ flag){
    const int c    = blockIdx.x >> 1;
    const int half = blockIdx.x & 1;
    const int col  = half*512 + threadIdx.x*2;
    if (flag[0]) km3_body<true>(nmean, Af, mb_ws, means_out, c, col);
    else         km3_body<false>(nmean, Af, mb_ws, means_out, c, col);
}

// ---------------------------------------------------------------------------
extern "C" void kernel_launch(void* const* d_in, const int* in_sizes, int n_in,
                              void* d_out, int out_size, void* d_ws, size_t ws_size,
                              hipStream_t stream){
    (void)in_sizes; (void)n_in; (void)out_size; (void)ws_size;
    const void* imean = d_in[0];  // [6,1024]
    const void* icov  = d_in[1];  // [6,6]
    const void* trans = d_in[2];  // [T,6,6]
    const void* nmean = d_in[3];  // [T,6,1024]
    const void* ncov  = d_in[4];  // [T,6,6]

    // workspace layout (8-byte types first; ~6 MB total)
    char* w = (char*)d_ws;
    double* Pd   = (double*)w; w += (size_t)CH*36*8;
    double* Qd   = (double*)w; w += (size_t)CH*36*8;
    double* Mb   = (double*)w; w += (size_t)CH*36*8;
    double* Mall = (double*)w; w += (size_t)T_STEPS*36*8;
    float*  Af   = (float*)w;  w += (size_t)T_STEPS*36*4;
    float*  Pf   = (float*)w;  w += (size_t)CH*36*4;
    uint32_t* masks = (uint32_t*)w; w += (size_t)T_STEPS*4;
    uint32_t* amask = (uint32_t*)w; w += (size_t)T_STEPS*4;
    uint32_t* flag  = (uint32_t*)w; w += 8;
    float* r_ws  = (float*)w;  w += (size_t)CH*6*DDIM*4;
    float* mb_ws = (float*)w;  w += (size_t)CH*6*DDIM*4;

    k0_detect<<<1, 64, 0, stream>>>(imean, flag);
    k1_chunk_compose<<<CH, 64, 0, stream>>>(trans, ncov, Pd, Qd, Af, Pf, flag);
    km1_chunk_r<<<2*CH, 256, 0, stream>>>(nmean, Af, r_ws, flag);
    km2_scan<<<4, 256, 0, stream>>>(imean, Pf, r_ws, mb_ws, flag);
    km3_final<<<2*CH, 256, 0, stream>>>(nmean, Af, mb_ws, d_out, flag);
    k2_boundary_scan<<<1, 64, 0, stream>>>(icov, Pd, Qd, Mb, flag);
    k3_expand_M<<<CH, 64, 0, stream>>>(trans, ncov, Mb, Mall, flag);
    k4_qr<<<T_STEPS/64, 64, 0, stream>>>(trans, ncov, icov, Mall, d_out, masks, flag);
    k5_scan<<<1, 64, 0, stream>>>(masks, amask);
    k6_apply<<<T_STEPS, 64, 0, stream>>>(d_out, amask, flag);
}